// Round 6
// baseline (123.269 us; speedup 1.0000x reference)
//
#include <hip/hip_runtime.h>
#include <hip/hip_bf16.h>
#include <math.h>

#define N_TOT 8192
#define HALF_N 4096
#define D_DIM 512
#define BM 256         // tile edge (256x256 tiles)
#define BK 64          // fp8 bytes per K-step; 8 K-steps
#define NKIT (D_DIM / BK)
#define NTILES 528     // 32*33/2 upper-triangle 256x256 tiles
#define THREADS 512    // 8 waves

// s_waitcnt imm: vmcnt[3:0] | expcnt<<4 | lgkmcnt<<8 (expcnt/lgkmcnt = max -> unconstrained)
#define WAIT_VM8 0xF78
#define WAIT_VM4 0xF74
#define WAIT_VM0 0xF70

typedef float f32x4_t __attribute__((ext_vector_type(4)));
typedef long long i64x2 __attribute__((ext_vector_type(2)));

typedef __attribute__((address_space(1))) unsigned int g_u32;
typedef __attribute__((address_space(3))) unsigned int l_u32;

// Kernel 1: L2-normalize rows of [p1;p2] -> fp8 e4m3 Z in k-PERMUTED layout
// (validated R9/R11): within each 64B k-block, source byte k (q=(k>>3)&3,
// h=(k>>5)&1) stored at q*16 + h*8 + (k&7). Both GEMM operands use the same
// bijection, so dot products are unaffected; a lane's two 8B MFMA k-pieces
// are one contiguous 16B chunk -> single ds_read_b128, zero bank conflicts.
__global__ __launch_bounds__(256) void k_normalize(
    const float* __restrict__ p1, const float* __restrict__ p2,
    unsigned char* __restrict__ zf8, float* __restrict__ rowsum,
    float* __restrict__ out)
{
    const int w = threadIdx.x >> 6;
    const int lane = threadIdx.x & 63;
    const int row = blockIdx.x * 4 + w;

    if (threadIdx.x < 4) rowsum[blockIdx.x * 4 + threadIdx.x] = 0.0f;
    if (blockIdx.x == 0 && threadIdx.x == 0) out[0] = 0.0f;

    const float* src = (row < HALF_N) ? p1 + (size_t)row * D_DIM
                                      : p2 + (size_t)(row - HALF_N) * D_DIM;
    float4 a = *(const float4*)(src + lane * 4);
    float4 b = *(const float4*)(src + 256 + lane * 4);
    float s = a.x*a.x + a.y*a.y + a.z*a.z + a.w*a.w
            + b.x*b.x + b.y*b.y + b.z*b.z + b.w*b.w;
    #pragma unroll
    for (int m = 1; m < 64; m <<= 1) s += __shfl_xor(s, m, 64);
    float inv = 1.0f / fmaxf(sqrtf(s), 1e-8f);

    int pk0 = __builtin_amdgcn_cvt_pk_fp8_f32(a.x * inv, a.y * inv, 0, false);
    pk0     = __builtin_amdgcn_cvt_pk_fp8_f32(a.z * inv, a.w * inv, pk0, true);
    int pk1 = __builtin_amdgcn_cvt_pk_fp8_f32(b.x * inv, b.y * inv, 0, false);
    pk1     = __builtin_amdgcn_cvt_pk_fp8_f32(b.z * inv, b.w * inv, pk1, true);

    unsigned char* dst = zf8 + (size_t)row * D_DIM;
    const int o0 = lane * 4;
    const int o1 = 256 + lane * 4;
    const int d0 = (o0 & ~63) + ((o0 >> 3) & 3) * 16 + ((o0 >> 5) & 1) * 8 + (o0 & 4);
    const int d1 = (o1 & ~63) + ((o1 >> 3) & 3) * 16 + ((o1 >> 5) & 1) * 8 + (o1 & 4);
    *(int*)(dst + d0) = pk0;
    *(int*)(dst + d1) = pk1;
}

// Kernel 2: upper-triangle 256x256 tiles of sim = Z*Z^T, fp8 MFMA 16x16x32.
// ROUND 5 lesson: counted-vmcnt triple-buffer == plain __syncthreads (69.5us,
// MfmaUtil 18.7% both) -> the load-wait was never the binder. The binder is
// the 2-PHASE LOCKSTEP: one barrier/K-step, all 8 waves burst 12 ds_reads
// together then MFMA together; nothing overlaps (T4/T5 measured null on
// 2-phase structures). ROUND 6: port the verified 256^2 8-PHASE template
// (m194-m201): per K-step, 4 quadrant phases of 16 MFMA, each phase =
// {2-6 ds_read_b128 || 1 global_load_lds (K-step +3) -> barrier ->
// setprio MFMA quadrant -> barrier}. LDS = ring of 4 K-step slots (128 KB).
// Trailing wait per K-step = vmcnt(8) (4 loads/slot x 2 slots legitimately
// in flight, never 0 until tail), placed BEFORE the trailing barrier so all
// waves' staging for the next slot is complete before anyone reads it.
// Unchanged proven pieces: k-permuted layout, chunk^((r>>1)&3) slot swizzle
// (0 conflicts), staging addresses, triangle mapping, epilogue,
// launch_bounds(512,2) (R2 lesson: tighter bound spills acc to scratch).
__global__ __launch_bounds__(THREADS, 2) void k_gemm(
    const unsigned char* __restrict__ zf8,
    float* __restrict__ rowsum, float* __restrict__ pos)
{
    __shared__ __align__(16) unsigned char As[4][BM * BK];  // 4 x 16 KB ring
    __shared__ __align__(16) unsigned char Bs[4][BM * BK];  // 4 x 16 KB ring

    const int tid = threadIdx.x;
    const int lane = tid & 63;
    const int w = tid >> 6;              // 0..7
    const int wr = w >> 2, wc = w & 3;   // wave grid 2 x 4: 128 rows x 64 cols
    const int q = lane >> 4, l15 = lane & 15;

    // XCD-aware bijective swizzle (528 = 8 * 66).
    const int t0 = blockIdx.x;
    const int t = (t0 & 7) * (NTILES / 8) + (t0 >> 3);

    // triangular block mapping: t -> (bx >= by)
    int bi = (int)((sqrtf(8.0f * (float)t + 1.0f) - 1.0f) * 0.5f);
    while ((bi + 1) * (bi + 2) / 2 <= t) ++bi;
    while (bi * (bi + 1) / 2 > t) --bi;
    const int bx = bi;                       // col tile (larger)
    const int by = t - bi * (bi + 1) / 2;    // row tile
    const bool isDiag = (bx == by);
    const bool hasPos = (bx - by == (HALF_N / BM));   // == 16
    const int rowBase = by * BM;
    const int colBase = bx * BM;

    // staging: 16B chunks, 1024 chunks per 256x64 tile, 512 threads ->
    // 2 chunks each for A and B. LDS slot cc of row r holds source chunk
    // cc ^ ((r>>1)&3) (R8/R11-proven swizzle).
    const int ci0 = tid;            // rows 0..127
    const int ci1 = tid + THREADS;  // rows 128..255
    const int r0 = ci0 >> 2, cc0 = ci0 & 3;
    const int r1 = ci1 >> 2, cc1 = ci1 & 3;
    const int gc0 = cc0 ^ ((r0 >> 1) & 3);
    const int gc1 = cc1 ^ ((r1 >> 1) & 3);

    const unsigned char* gA0 = zf8 + (size_t)(rowBase + r0) * D_DIM + gc0 * 16;
    const unsigned char* gA1 = zf8 + (size_t)(rowBase + r1) * D_DIM + gc1 * 16;
    const unsigned char* gB0 = zf8 + (size_t)(colBase + r0) * D_DIM + gc0 * 16;
    const unsigned char* gB1 = zf8 + (size_t)(colBase + r1) * D_DIM + gc1 * 16;

    auto stageAll = [&](int buf, int kblk) {
        const int kb = kblk * BK;
        __builtin_amdgcn_global_load_lds((const g_u32*)(gA0 + kb), (l_u32*)&As[buf][ci0 * 16], 16, 0, 0);
        __builtin_amdgcn_global_load_lds((const g_u32*)(gA1 + kb), (l_u32*)&As[buf][ci1 * 16], 16, 0, 0);
        __builtin_amdgcn_global_load_lds((const g_u32*)(gB0 + kb), (l_u32*)&Bs[buf][ci0 * 16], 16, 0, 0);
        __builtin_amdgcn_global_load_lds((const g_u32*)(gB1 + kb), (l_u32*)&Bs[buf][ci1 * 16], 16, 0, 0);
    };

    f32x4_t acc[8][4] = {};

#define READ_A(i) do { const int ra_ = wr * 128 + (i) * 16 + l15; \
        aF[i] = *(const i64x2*)&As[cur][ra_ * BK + (q ^ ((ra_ >> 1) & 3)) * 16]; } while (0)
#define READ_B(j) do { const int rb_ = wc * 64 + (j) * 16 + l15; \
        bF[j] = *(const i64x2*)&Bs[cur][rb_ * BK + (q ^ ((rb_ >> 1) & 3)) * 16]; } while (0)
#define QUAD(ih, jh) do { \
        __builtin_amdgcn_s_setprio(1); \
        _Pragma("unroll") for (int h_ = 0; h_ < 2; h_++) \
        _Pragma("unroll") for (int i_ = 0; i_ < 4; i_++) \
        _Pragma("unroll") for (int j_ = 0; j_ < 2; j_++) \
            acc[(ih) * 4 + i_][(jh) * 2 + j_] = __builtin_amdgcn_mfma_f32_16x16x32_fp8_fp8( \
                aF[(ih) * 4 + i_][h_], bF[(jh) * 2 + j_][h_], acc[(ih) * 4 + i_][(jh) * 2 + j_], 0, 0, 0); \
        __builtin_amdgcn_s_setprio(0); } while (0)

    // prologue: fill slots 0,1,2 (12 loads); wait slot 0 (leave 8 in flight).
    stageAll(0, 0);
    stageAll(1, 1);
    stageAll(2, 2);
    __builtin_amdgcn_s_waitcnt(WAIT_VM8);
    __builtin_amdgcn_s_barrier();
    __builtin_amdgcn_sched_barrier(0);

    #pragma unroll
    for (int it = 0; it < NKIT; it++) {
        const int cur = it & 3;
        const int nslot = (it + 3) & 3;
        const bool doStage = (it + 3) < NKIT;
        const int kb = (it + 3) * BK;

        i64x2 aF[8], bF[4];

        // ---- phase 0: aF0-3, bF0-1 | stage A#1 | barrier | QUAD(0,0) ----
        READ_A(0); READ_A(1); READ_A(2); READ_A(3);
        READ_B(0); READ_B(1);
        if (doStage)
            __builtin_amdgcn_global_load_lds((const g_u32*)(gA0 + kb), (l_u32*)&As[nslot][ci0 * 16], 16, 0, 0);
        __builtin_amdgcn_s_barrier();
        QUAD(0, 0);
        __builtin_amdgcn_s_barrier();

        // ---- phase 1: bF2-3 | stage A#2 | barrier | QUAD(0,1) ----
        READ_B(2); READ_B(3);
        if (doStage)
            __builtin_amdgcn_global_load_lds((const g_u32*)(gA1 + kb), (l_u32*)&As[nslot][ci1 * 16], 16, 0, 0);
        __builtin_amdgcn_s_barrier();
        QUAD(0, 1);
        __builtin_amdgcn_s_barrier();

        // ---- phase 2: aF4-7 | stage B#1 | barrier | QUAD(1,0) ----
        READ_A(4); READ_A(5); READ_A(6); READ_A(7);
        if (doStage)
            __builtin_amdgcn_global_load_lds((const g_u32*)(gB0 + kb), (l_u32*)&Bs[nslot][ci0 * 16], 16, 0, 0);
        __builtin_amdgcn_s_barrier();
        QUAD(1, 0);
        __builtin_amdgcn_s_barrier();

        // ---- phase 3: stage B#2 | barrier | QUAD(1,1) | vmcnt | barrier ----
        if (doStage)
            __builtin_amdgcn_global_load_lds((const g_u32*)(gB1 + kb), (l_u32*)&Bs[nslot][ci1 * 16], 16, 0, 0);
        __builtin_amdgcn_s_barrier();
        QUAD(1, 1);
        if (it < NKIT - 1) {
            // guarantee slot it+1 fully staged (ALL waves) before next reads:
            // per-wave wait, then barrier. Outstanding budget: slots it+2,it+3.
            if (it < 5)       __builtin_amdgcn_s_waitcnt(WAIT_VM8);
            else if (it == 5) __builtin_amdgcn_s_waitcnt(WAIT_VM4);
            else              __builtin_amdgcn_s_waitcnt(WAIT_VM0);
            __builtin_amdgcn_s_barrier();
            __builtin_amdgcn_sched_barrier(0);
        }
    }
#undef READ_A
#undef READ_B
#undef QUAD

    // Epilogue. C/D layout (16x16 family): col = lane&15, row = (lane>>4)*4 + reg.
    float colacc[4] = {0.f, 0.f, 0.f, 0.f};
    #pragma unroll
    for (int i = 0; i < 8; i++) {
        #pragma unroll
        for (int r = 0; r < 4; r++) {
            const int row = rowBase + wr * 128 + i * 16 + q * 4 + r;
            float rs = 0.0f;
            #pragma unroll
            for (int j = 0; j < 4; j++) {
                const int col = colBase + wc * 64 + j * 16 + l15;
                const float c = acc[i][j][r];
                float e = __expf(c);
                if (isDiag && col == row) e = 0.0f;
                rs += e;
                colacc[j] += e;
                if (hasPos && col == row + HALF_N) { pos[row] = c; pos[col] = c; }
            }
            rs += __shfl_xor(rs, 1); rs += __shfl_xor(rs, 2);
            rs += __shfl_xor(rs, 4); rs += __shfl_xor(rs, 8);
            if (l15 == 0) atomicAdd(&rowsum[row], rs);
        }
    }
    if (!isDiag) {
        #pragma unroll
        for (int j = 0; j < 4; j++) {
            float cs = colacc[j];
            cs += __shfl_xor(cs, 16);
            cs += __shfl_xor(cs, 32);
            if (q == 0) atomicAdd(&rowsum[colBase + wc * 64 + j * 16 + l15], cs);
        }
    }
}

// Kernel 3: mean over rows of (log(rowsum) - pos) -> scalar (out pre-zeroed).
__global__ __launch_bounds__(256) void k_finalize(
    const float* __restrict__ rowsum, const float* __restrict__ pos,
    float* __restrict__ out)
{
    const int t = threadIdx.x;
    const int i = blockIdx.x * 256 + t;
    float s = logf(rowsum[i]) - pos[i];
    #pragma unroll
    for (int m = 1; m < 64; m <<= 1) s += __shfl_xor(s, m, 64);
    __shared__ float red[4];
    if ((t & 63) == 0) red[t >> 6] = s;
    __syncthreads();
    if (t == 0)
        atomicAdd(out, (red[0] + red[1] + red[2] + red[3]) * (1.0f / (float)N_TOT));
}

extern "C" void kernel_launch(void* const* d_in, const int* in_sizes, int n_in,
                              void* d_out, int out_size, void* d_ws, size_t ws_size,
                              hipStream_t stream) {
    const float* p1 = (const float*)d_in[0];
    const float* p2 = (const float*)d_in[1];

    unsigned char* zf8 = (unsigned char*)d_ws;                          // 4 MB
    float* rowsum = (float*)((char*)d_ws + (size_t)N_TOT * D_DIM);      // 32 KB
    float* pos    = rowsum + N_TOT;                                     // 32 KB
    float* outp   = (float*)d_out;

    k_normalize<<<N_TOT / 4, 256, 0, stream>>>(p1, p2, zf8, rowsum, outp);
    k_gemm<<<NTILES, THREADS, 0, stream>>>(zf8, rowsum, pos);
    k_finalize<<<N_TOT / 256, 256, 0, stream>>>(rowsum, pos, outp);
}

// Round 7
// 122.899 us; speedup vs baseline: 1.0030x; 1.0030x over previous
//
#include <hip/hip_runtime.h>
#include <hip/hip_bf16.h>
#include <math.h>

#define N_TOT 8192
#define HALF_N 4096
#define D_DIM 512
#define BM 256         // tile edge (256x256 tiles)
#define BK 64          // fp8 bytes per K-step; 8 K-steps
#define NKIT (D_DIM / BK)
#define NTILES 528     // 32*33/2 upper-triangle 256x256 tiles
#define THREADS 512    // 8 waves

// s_waitcnt imm: vmcnt[3:0] | expcnt<<4 | lgkmcnt<<8 (expcnt/lgkmcnt = max -> unconstrained)
#define WAIT_VM0 0xF70

typedef float f32x4_t __attribute__((ext_vector_type(4)));
typedef long long i64x2 __attribute__((ext_vector_type(2)));

typedef __attribute__((address_space(1))) unsigned int g_u32;
typedef __attribute__((address_space(3))) unsigned int l_u32;

// Kernel 1: L2-normalize rows of [p1;p2] -> fp8 e4m3 Z in k-PERMUTED layout
// (validated R9/R11): within each 64B k-block, source byte k (q=(k>>3)&3,
// h=(k>>5)&1) stored at q*16 + h*8 + (k&7). Both GEMM operands use the same
// bijection, so dot products are unaffected; a lane's two 8B MFMA k-pieces
// are one contiguous 16B chunk -> single ds_read_b128, zero bank conflicts.
__global__ __launch_bounds__(256) void k_normalize(
    const float* __restrict__ p1, const float* __restrict__ p2,
    unsigned char* __restrict__ zf8, float* __restrict__ rowsum,
    float* __restrict__ out)
{
    const int w = threadIdx.x >> 6;
    const int lane = threadIdx.x & 63;
    const int row = blockIdx.x * 4 + w;

    if (threadIdx.x < 4) rowsum[blockIdx.x * 4 + threadIdx.x] = 0.0f;
    if (blockIdx.x == 0 && threadIdx.x == 0) out[0] = 0.0f;

    const float* src = (row < HALF_N) ? p1 + (size_t)row * D_DIM
                                      : p2 + (size_t)(row - HALF_N) * D_DIM;
    float4 a = *(const float4*)(src + lane * 4);
    float4 b = *(const float4*)(src + 256 + lane * 4);
    float s = a.x*a.x + a.y*a.y + a.z*a.z + a.w*a.w
            + b.x*b.x + b.y*b.y + b.z*b.z + b.w*b.w;
    #pragma unroll
    for (int m = 1; m < 64; m <<= 1) s += __shfl_xor(s, m, 64);
    float inv = 1.0f / fmaxf(sqrtf(s), 1e-8f);

    int pk0 = __builtin_amdgcn_cvt_pk_fp8_f32(a.x * inv, a.y * inv, 0, false);
    pk0     = __builtin_amdgcn_cvt_pk_fp8_f32(a.z * inv, a.w * inv, pk0, true);
    int pk1 = __builtin_amdgcn_cvt_pk_fp8_f32(b.x * inv, b.y * inv, 0, false);
    pk1     = __builtin_amdgcn_cvt_pk_fp8_f32(b.z * inv, b.w * inv, pk1, true);

    unsigned char* dst = zf8 + (size_t)row * D_DIM;
    const int o0 = lane * 4;
    const int o1 = 256 + lane * 4;
    const int d0 = (o0 & ~63) + ((o0 >> 3) & 3) * 16 + ((o0 >> 5) & 1) * 8 + (o0 & 4);
    const int d1 = (o1 & ~63) + ((o1 >> 3) & 3) * 16 + ((o1 >> 5) & 1) * 8 + (o1 & 4);
    *(int*)(dst + d0) = pk0;
    *(int*)(dst + d1) = pk1;
}

// Kernel 2: upper-triangle 256x256 tiles of sim = Z*Z^T, fp8 MFMA 16x16x32.
// ROUND 6 lesson (counters): 8-phase + 4-slot ring (128 KB LDS) = 60.9us,
// MfmaUtil 21%, Occupancy 14% -- the 128 KB ring forced 1 block/CU, so every
// barrier/prologue/epilogue stall was EXPOSED (no co-resident block to fill
// gaps), and 528 tiles at 1/CU left a 16-CU third round (~1/3 of makespan
// nearly idle). ROUND 7: 2-SLOT ring (64 KB) -> 2 blocks/CU co-residency
// (m114 inter-block overlap; unified-RF fits: ~240 regs/wave x 4 waves/SIMD).
// Prefetch distance 1: the 4 stage-loads for slot it+1 are spread across
// phases 0-3 of K-step it, so the trailing vmcnt(0) drains loads issued
// 600-2400 cyc earlier (L2 latency covered; R5 proved counted-vs-drain null
// when cover suffices). Ordering: all reads of a slot are in registers
// (compiler lgkm waits before each QUAD) before its last-read-phase barrier;
// stages into it are issued after the NEXT K-step-boundary barrier.
// sched_barrier(0) after each leading barrier pins the phase structure
// (sparse placement -- m141 lesson). Unchanged proven pieces: k-permuted
// layout, chunk^((r>>1)&3) slot swizzle (0 conflicts), triangle mapping,
// epilogue, launch_bounds(512,2) (R2: tighter bound spills acc to scratch).
__global__ __launch_bounds__(THREADS, 2) void k_gemm(
    const unsigned char* __restrict__ zf8,
    float* __restrict__ rowsum, float* __restrict__ pos)
{
    __shared__ __align__(16) unsigned char As[2][BM * BK];  // 2 x 16 KB
    __shared__ __align__(16) unsigned char Bs[2][BM * BK];  // 2 x 16 KB

    const int tid = threadIdx.x;
    const int lane = tid & 63;
    const int w = tid >> 6;              // 0..7
    const int wr = w >> 2, wc = w & 3;   // wave grid 2 x 4: 128 rows x 64 cols
    const int q = lane >> 4, l15 = lane & 15;

    // XCD-aware bijective swizzle (528 = 8 * 66).
    const int t0 = blockIdx.x;
    const int t = (t0 & 7) * (NTILES / 8) + (t0 >> 3);

    // triangular block mapping: t -> (bx >= by)
    int bi = (int)((sqrtf(8.0f * (float)t + 1.0f) - 1.0f) * 0.5f);
    while ((bi + 1) * (bi + 2) / 2 <= t) ++bi;
    while (bi * (bi + 1) / 2 > t) --bi;
    const int bx = bi;                       // col tile (larger)
    const int by = t - bi * (bi + 1) / 2;    // row tile
    const bool isDiag = (bx == by);
    const bool hasPos = (bx - by == (HALF_N / BM));   // == 16
    const int rowBase = by * BM;
    const int colBase = bx * BM;

    // staging: 16B chunks, 1024 chunks per 256x64 tile, 512 threads ->
    // 2 chunks each for A and B. LDS slot cc of row r holds source chunk
    // cc ^ ((r>>1)&3) (R8/R11-proven swizzle).
    const int ci0 = tid;            // rows 0..127
    const int ci1 = tid + THREADS;  // rows 128..255
    const int r0 = ci0 >> 2, cc0 = ci0 & 3;
    const int r1 = ci1 >> 2, cc1 = ci1 & 3;
    const int gc0 = cc0 ^ ((r0 >> 1) & 3);
    const int gc1 = cc1 ^ ((r1 >> 1) & 3);

    const unsigned char* gA0 = zf8 + (size_t)(rowBase + r0) * D_DIM + gc0 * 16;
    const unsigned char* gA1 = zf8 + (size_t)(rowBase + r1) * D_DIM + gc1 * 16;
    const unsigned char* gB0 = zf8 + (size_t)(colBase + r0) * D_DIM + gc0 * 16;
    const unsigned char* gB1 = zf8 + (size_t)(colBase + r1) * D_DIM + gc1 * 16;

    f32x4_t acc[8][4] = {};

#define READ_A(i) do { const int ra_ = wr * 128 + (i) * 16 + l15; \
        aF[i] = *(const i64x2*)&As[cur][ra_ * BK + (q ^ ((ra_ >> 1) & 3)) * 16]; } while (0)
#define READ_B(j) do { const int rb_ = wc * 64 + (j) * 16 + l15; \
        bF[j] = *(const i64x2*)&Bs[cur][rb_ * BK + (q ^ ((rb_ >> 1) & 3)) * 16]; } while (0)
#define QUAD(ih, jh) do { \
        __builtin_amdgcn_s_setprio(1); \
        _Pragma("unroll") for (int h_ = 0; h_ < 2; h_++) \
        _Pragma("unroll") for (int i_ = 0; i_ < 4; i_++) \
        _Pragma("unroll") for (int j_ = 0; j_ < 2; j_++) \
            acc[(ih) * 4 + i_][(jh) * 2 + j_] = __builtin_amdgcn_mfma_f32_16x16x32_fp8_fp8( \
                aF[(ih) * 4 + i_][h_], bF[(jh) * 2 + j_][h_], acc[(ih) * 4 + i_][(jh) * 2 + j_], 0, 0, 0); \
        __builtin_amdgcn_s_setprio(0); } while (0)
#define STAGE1(gp, arr, ci) \
        __builtin_amdgcn_global_load_lds((const g_u32*)((gp) + kb), (l_u32*)&arr[nxt][(ci) * 16], 16, 0, 0)

    // prologue: fill slot 0 (4 loads), drain, sync.
    {
        const int nxt = 0; const int kb = 0;
        STAGE1(gA0, As, ci0); STAGE1(gA1, As, ci1);
        STAGE1(gB0, Bs, ci0); STAGE1(gB1, Bs, ci1);
    }
    __builtin_amdgcn_s_waitcnt(WAIT_VM0);
    __builtin_amdgcn_s_barrier();
    __builtin_amdgcn_sched_barrier(0);

    #pragma unroll
    for (int it = 0; it < NKIT; it++) {
        const int cur = it & 1;
        const int nxt = cur ^ 1;
        const bool doStage = (it + 1 < NKIT);
        const int kb = (it + 1) * BK;

        i64x2 aF[8], bF[4];

        // ---- phase 0: aF0-3, bF0-1 | stage A#1 -> nxt | barrier | QUAD(0,0) ----
        READ_A(0); READ_A(1); READ_A(2); READ_A(3);
        READ_B(0); READ_B(1);
        if (doStage) STAGE1(gA0, As, ci0);
        __builtin_amdgcn_s_barrier();
        __builtin_amdgcn_sched_barrier(0);
        QUAD(0, 0);
        __builtin_amdgcn_s_barrier();

        // ---- phase 1: bF2-3 | stage A#2 -> nxt | barrier | QUAD(0,1) ----
        READ_B(2); READ_B(3);
        if (doStage) STAGE1(gA1, As, ci1);
        __builtin_amdgcn_s_barrier();
        __builtin_amdgcn_sched_barrier(0);
        QUAD(0, 1);
        __builtin_amdgcn_s_barrier();

        // ---- phase 2: aF4-7 | stage B#1 -> nxt | barrier | QUAD(1,0) ----
        READ_A(4); READ_A(5); READ_A(6); READ_A(7);
        if (doStage) STAGE1(gB0, Bs, ci0);
        __builtin_amdgcn_s_barrier();
        __builtin_amdgcn_sched_barrier(0);
        QUAD(1, 0);
        __builtin_amdgcn_s_barrier();

        // ---- phase 3: stage B#2 -> nxt | barrier | QUAD(1,1) | vm0 | barrier ----
        if (doStage) STAGE1(gB1, Bs, ci1);
        __builtin_amdgcn_s_barrier();
        __builtin_amdgcn_sched_barrier(0);
        QUAD(1, 1);
        if (doStage) {
            // slot nxt's 4 loads were issued in phases 0-3 (600-2400 cyc ago);
            // vmcnt(0) here is a covered wait, then barrier publishes to all.
            __builtin_amdgcn_s_waitcnt(WAIT_VM0);
            __builtin_amdgcn_s_barrier();
            __builtin_amdgcn_sched_barrier(0);
        }
    }
#undef READ_A
#undef READ_B
#undef QUAD
#undef STAGE1

    // Epilogue. C/D layout (16x16 family): col = lane&15, row = (lane>>4)*4 + reg.
    float colacc[4] = {0.f, 0.f, 0.f, 0.f};
    #pragma unroll
    for (int i = 0; i < 8; i++) {
        #pragma unroll
        for (int r = 0; r < 4; r++) {
            const int row = rowBase + wr * 128 + i * 16 + q * 4 + r;
            float rs = 0.0f;
            #pragma unroll
            for (int j = 0; j < 4; j++) {
                const int col = colBase + wc * 64 + j * 16 + l15;
                const float c = acc[i][j][r];
                float e = __expf(c);
                if (isDiag && col == row) e = 0.0f;
                rs += e;
                colacc[j] += e;
                if (hasPos && col == row + HALF_N) { pos[row] = c; pos[col] = c; }
            }
            rs += __shfl_xor(rs, 1); rs += __shfl_xor(rs, 2);
            rs += __shfl_xor(rs, 4); rs += __shfl_xor(rs, 8);
            if (l15 == 0) atomicAdd(&rowsum[row], rs);
        }
    }
    if (!isDiag) {
        #pragma unroll
        for (int j = 0; j < 4; j++) {
            float cs = colacc[j];
            cs += __shfl_xor(cs, 16);
            cs += __shfl_xor(cs, 32);
            if (q == 0) atomicAdd(&rowsum[colBase + wc * 64 + j * 16 + l15], cs);
        }
    }
}

// Kernel 3: mean over rows of (log(rowsum) - pos) -> scalar (out pre-zeroed).
__global__ __launch_bounds__(256) void k_finalize(
    const float* __restrict__ rowsum, const float* __restrict__ pos,
    float* __restrict__ out)
{
    const int t = threadIdx.x;
    const int i = blockIdx.x * 256 + t;
    float s = logf(rowsum[i]) - pos[i];
    #pragma unroll
    for (int m = 1; m < 64; m <<= 1) s += __shfl_xor(s, m, 64);
    __shared__ float red[4];
    if ((t & 63) == 0) red[t >> 6] = s;
    __syncthreads();
    if (t == 0)
        atomicAdd(out, (red[0] + red[1] + red[2] + red[3]) * (1.0f / (float)N_TOT));
}

extern "C" void kernel_launch(void* const* d_in, const int* in_sizes, int n_in,
                              void* d_out, int out_size, void* d_ws, size_t ws_size,
                              hipStream_t stream) {
    const float* p1 = (const float*)d_in[0];
    const float* p2 = (const float*)d_in[1];

    unsigned char* zf8 = (unsigned char*)d_ws;                          // 4 MB
    float* rowsum = (float*)((char*)d_ws + (size_t)N_TOT * D_DIM);      // 32 KB
    float* pos    = rowsum + N_TOT;                                     // 32 KB
    float* outp   = (float*)d_out;

    k_normalize<<<N_TOT / 4, 256, 0, stream>>>(p1, p2, zf8, rowsum, outp);
    k_gemm<<<NTILES, THREADS, 0, stream>>>(zf8, rowsum, pos);
    k_finalize<<<N_TOT / 256, 256, 0, stream>>>(rowsum, pos, outp);
}

// Round 8
// 111.489 us; speedup vs baseline: 1.1057x; 1.1023x over previous
//
#include <hip/hip_runtime.h>
#include <hip/hip_bf16.h>
#include <math.h>

#define N_TOT 8192
#define HALF_N 4096
#define D_DIM 512
#define BM 128         // tile edge (128x128 tiles)
#define BK 64          // fp8 bytes per K-step; 8 K-steps
#define NKIT (D_DIM / BK)
#define NTILES 2080    // 64*65/2 upper-triangle 128x128 tiles
#define THREADS 512    // 8 thin waves -> small per-wave state

// s_waitcnt imm: vmcnt[3:0] | expcnt<<4 | lgkmcnt<<8 (expcnt/lgkmcnt = max -> unconstrained)
#define WAIT_VM0 0xF70

typedef float f32x4_t __attribute__((ext_vector_type(4)));
typedef long long i64x2 __attribute__((ext_vector_type(2)));

typedef __attribute__((address_space(1))) unsigned int g_u32;
typedef __attribute__((address_space(3))) unsigned int l_u32;

// Kernel 1: L2-normalize rows of [p1;p2] -> fp8 e4m3 Z in k-PERMUTED layout
// (validated R9/R11): within each 64B k-block, source byte k (q=(k>>3)&3,
// h=(k>>5)&1) stored at q*16 + h*8 + (k&7). Both GEMM operands use the same
// bijection, so dot products are unaffected; a lane's two 8B MFMA k-pieces
// are one contiguous 16B chunk -> single ds_read_b128, zero bank conflicts.
__global__ __launch_bounds__(256) void k_normalize(
    const float* __restrict__ p1, const float* __restrict__ p2,
    unsigned char* __restrict__ zf8, float* __restrict__ rowsum,
    float* __restrict__ out)
{
    const int w = threadIdx.x >> 6;
    const int lane = threadIdx.x & 63;
    const int row = blockIdx.x * 4 + w;

    if (threadIdx.x < 4) rowsum[blockIdx.x * 4 + threadIdx.x] = 0.0f;
    if (blockIdx.x == 0 && threadIdx.x == 0) out[0] = 0.0f;

    const float* src = (row < HALF_N) ? p1 + (size_t)row * D_DIM
                                      : p2 + (size_t)(row - HALF_N) * D_DIM;
    float4 a = *(const float4*)(src + lane * 4);
    float4 b = *(const float4*)(src + 256 + lane * 4);
    float s = a.x*a.x + a.y*a.y + a.z*a.z + a.w*a.w
            + b.x*b.x + b.y*b.y + b.z*b.z + b.w*b.w;
    #pragma unroll
    for (int m = 1; m < 64; m <<= 1) s += __shfl_xor(s, m, 64);
    float inv = 1.0f / fmaxf(sqrtf(s), 1e-8f);

    int pk0 = __builtin_amdgcn_cvt_pk_fp8_f32(a.x * inv, a.y * inv, 0, false);
    pk0     = __builtin_amdgcn_cvt_pk_fp8_f32(a.z * inv, a.w * inv, pk0, true);
    int pk1 = __builtin_amdgcn_cvt_pk_fp8_f32(b.x * inv, b.y * inv, 0, false);
    pk1     = __builtin_amdgcn_cvt_pk_fp8_f32(b.z * inv, b.w * inv, pk1, true);

    unsigned char* dst = zf8 + (size_t)row * D_DIM;
    const int o0 = lane * 4;
    const int o1 = 256 + lane * 4;
    const int d0 = (o0 & ~63) + ((o0 >> 3) & 3) * 16 + ((o0 >> 5) & 1) * 8 + (o0 & 4);
    const int d1 = (o1 & ~63) + ((o1 >> 3) & 3) * 16 + ((o1 >> 5) & 1) * 8 + (o1 & 4);
    *(int*)(dst + d0) = pk0;
    *(int*)(dst + d1) = pk1;
}

// Kernel 2: upper-triangle 128x128 tiles of sim = Z*Z^T, fp8 MFMA 16x16x32.
// ROUND 7 lesson (counters + register math): the 256^2 line can NEVER
// co-reside -- 128-float acc + ~104 arch regs = 232/wave, and the RF is 512
// regs/wave-slot/SIMD -> 2 waves/SIMD = 1 block/CU, occupancy stuck at 14%,
// all fixed costs exposed; every 256^2 variant (60-70us) lost to the round-0
// 128^2 baseline (~45us, 3 blocks/CU). CO-RESIDENCY IS THE LEVER (m114).
// ROUND 8: thin-wave 128^2: 8 waves x (64x32 out) -> acc = 32 floats,
// ~90-110 regs/wave, launch_bounds(512,4) caps at 128 (comfortable);
// double-buffer LDS = 32 KB -> 2 blocks/CU = 16 waves/CU. Simple R3-proven
// schedule (stage-after-barrier, vm0 drain: R5/R7 proved counted==drain when
// the stage was issued a full iteration earlier). Two co-resident blocks at
// independent phases hide each other's prologue/epilogue and give setprio
// real role diversity. k-permuted layout + chunk^((r>>1)&3) slot swizzle
// (0 bank conflicts) unchanged. XCD swizzle: 2080 = 8*260, bijective.
__global__ __launch_bounds__(THREADS, 4) void k_gemm(
    const unsigned char* __restrict__ zf8,
    float* __restrict__ rowsum, float* __restrict__ pos)
{
    __shared__ __align__(16) unsigned char As[2][BM * BK];  // 2 x 8 KB
    __shared__ __align__(16) unsigned char Bs[2][BM * BK];  // 2 x 8 KB

    const int tid = threadIdx.x;
    const int lane = tid & 63;
    const int w = tid >> 6;              // 0..7
    const int wr = w >> 2, wc = w & 3;   // wave grid 2 x 4: 64-row x 32-col per wave
    const int q = lane >> 4, l15 = lane & 15;

    // XCD-aware bijective swizzle (2080 = 8 * 260).
    const int t0 = blockIdx.x;
    const int t = (t0 & 7) * (NTILES / 8) + (t0 >> 3);

    // triangular block mapping: t -> (bx >= by)
    int bi = (int)((sqrtf(8.0f * (float)t + 1.0f) - 1.0f) * 0.5f);
    while ((bi + 1) * (bi + 2) / 2 <= t) ++bi;
    while (bi * (bi + 1) / 2 > t) --bi;
    const int bx = bi;                       // col tile (larger)
    const int by = t - bi * (bi + 1) / 2;    // row tile
    const bool isDiag = (bx == by);
    const bool hasPos = (bx - by == (HALF_N / BM));   // == 32
    const int rowBase = by * BM;
    const int colBase = bx * BM;

    // staging: 16B chunks; 128 rows x 4 chunks = 512 chunks per matrix =
    // 1 A-chunk + 1 B-chunk per thread. LDS slot cc of row r holds source
    // chunk cc ^ ((r>>1)&3) (R8/R11-proven swizzle).
    const int r0 = tid >> 2, cc0 = tid & 3;
    const int gc0 = cc0 ^ ((r0 >> 1) & 3);
    const unsigned char* gA = zf8 + (size_t)(rowBase + r0) * D_DIM + gc0 * 16;
    const unsigned char* gB = zf8 + (size_t)(colBase + r0) * D_DIM + gc0 * 16;

    auto stage = [&](int buf, int kblk) {
        const int kb = kblk * BK;
        __builtin_amdgcn_global_load_lds((const g_u32*)(gA + kb), (l_u32*)&As[buf][tid * 16], 16, 0, 0);
        __builtin_amdgcn_global_load_lds((const g_u32*)(gB + kb), (l_u32*)&Bs[buf][tid * 16], 16, 0, 0);
    };

    // precomputed per-lane fragment byte offsets within one 8 KB buffer
    int aOff[4], bOff[2];
    #pragma unroll
    for (int i = 0; i < 4; i++) {
        const int ra = wr * 64 + i * 16 + l15;
        aOff[i] = ra * BK + (q ^ ((ra >> 1) & 3)) * 16;
    }
    #pragma unroll
    for (int j = 0; j < 2; j++) {
        const int rb = wc * 32 + j * 16 + l15;
        bOff[j] = rb * BK + (q ^ ((rb >> 1) & 3)) * 16;
    }

    f32x4_t acc[4][2] = {};

    stage(0, 0);

    #pragma unroll
    for (int it = 0; it < NKIT; it++) {
        const int cur = it & 1;
        // my stage(it) was issued a full iteration ago (except it==0);
        // vm0 is a covered wait, barrier publishes all waves' staging.
        __builtin_amdgcn_s_waitcnt(WAIT_VM0);
        __builtin_amdgcn_s_barrier();
        if (it + 1 < NKIT) stage(cur ^ 1, it + 1);

        i64x2 aF[4], bF[2];
        #pragma unroll
        for (int i = 0; i < 4; i++) aF[i] = *(const i64x2*)&As[cur][aOff[i]];
        #pragma unroll
        for (int j = 0; j < 2; j++) bF[j] = *(const i64x2*)&Bs[cur][bOff[j]];

        __builtin_amdgcn_s_setprio(1);
        #pragma unroll
        for (int h = 0; h < 2; h++)
            #pragma unroll
            for (int i = 0; i < 4; i++)
                #pragma unroll
                for (int j = 0; j < 2; j++)
                    acc[i][j] = __builtin_amdgcn_mfma_f32_16x16x32_fp8_fp8(
                        aF[i][h], bF[j][h], acc[i][j], 0, 0, 0);
        __builtin_amdgcn_s_setprio(0);
        // reads of buf cur are in regs (lgkm-waited before MFMA), so next
        // iteration's stage into cur is WAW-safe after its top barrier.
    }

    // Epilogue. C/D layout (16x16 family): col = lane&15, row = (lane>>4)*4 + reg.
    float colacc[2] = {0.f, 0.f};
    #pragma unroll
    for (int i = 0; i < 4; i++) {
        #pragma unroll
        for (int r = 0; r < 4; r++) {
            const int row = rowBase + wr * 64 + i * 16 + q * 4 + r;
            float rs = 0.0f;
            #pragma unroll
            for (int j = 0; j < 2; j++) {
                const int col = colBase + wc * 32 + j * 16 + l15;
                const float c = acc[i][j][r];
                float e = __expf(c);
                if (isDiag && col == row) e = 0.0f;
                rs += e;
                colacc[j] += e;
                if (hasPos && col == row + HALF_N) { pos[row] = c; pos[col] = c; }
            }
            rs += __shfl_xor(rs, 1); rs += __shfl_xor(rs, 2);
            rs += __shfl_xor(rs, 4); rs += __shfl_xor(rs, 8);
            if (l15 == 0) atomicAdd(&rowsum[row], rs);
        }
    }
    if (!isDiag) {
        #pragma unroll
        for (int j = 0; j < 2; j++) {
            float cs = colacc[j];
            cs += __shfl_xor(cs, 16);
            cs += __shfl_xor(cs, 32);
            if (q == 0) atomicAdd(&rowsum[colBase + wc * 32 + j * 16 + l15], cs);
        }
    }
}

// Kernel 3: mean over rows of (log(rowsum) - pos) -> scalar (out pre-zeroed).
__global__ __launch_bounds__(256) void k_finalize(
    const float* __restrict__ rowsum, const float* __restrict__ pos,
    float* __restrict__ out)
{
    const int t = threadIdx.x;
    const int i = blockIdx.x * 256 + t;
    float s = logf(rowsum[i]) - pos[i];
    #pragma unroll
    for (int m = 1; m < 64; m <<= 1) s += __shfl_xor(s, m, 64);
    __shared__ float red[4];
    if ((t & 63) == 0) red[t >> 6] = s;
    __syncthreads();
    if (t == 0)
        atomicAdd(out, (red[0] + red[1] + red[2] + red[3]) * (1.0f / (float)N_TOT));
}

extern "C" void kernel_launch(void* const* d_in, const int* in_sizes, int n_in,
                              void* d_out, int out_size, void* d_ws, size_t ws_size,
                              hipStream_t stream) {
    const float* p1 = (const float*)d_in[0];
    const float* p2 = (const float*)d_in[1];

    unsigned char* zf8 = (unsigned char*)d_ws;                          // 4 MB
    float* rowsum = (float*)((char*)d_ws + (size_t)N_TOT * D_DIM);      // 32 KB
    float* pos    = rowsum + N_TOT;                                     // 32 KB
    float* outp   = (float*)d_out;

    k_normalize<<<N_TOT / 4, 256, 0, stream>>>(p1, p2, zf8, rowsum, outp);
    k_gemm<<<NTILES, THREADS, 0, stream>>>(zf8, rowsum, pos);
    k_finalize<<<N_TOT / 256, 256, 0, stream>>>(rowsum, pos, outp);
}